// Round 15
// baseline (1183.747 us; speedup 1.0000x reference)
//
#include <hip/hip_runtime.h>

// InteractionNetwork — decomposed (R13 structure, occupancy push):
//   prep_x : x -> bf16 table xb (6.4 MB): edge gathers read 128B rows.
//   K_mlp  : edge (two single-set dispatches) / node MLP+LN.
//            __launch_bounds__(512,6) + NO software prefetch (saves 12
//            persistent regs) -> target 3 blocks/CU (was 2; reg-cliff).
//   K_agg  : CSR segment-sum, both sets, 4-wide row loads per lane-group.
//   sort   : hist -> parallel chunk-scan -> scatter(perm).
// MLP: OUT^T = W^T * X^T, weight frags persistent+deduped in regs, activations
// through XOR-swizzled LDS, 4 barriers/tile, residual re-read from global (L2).

#define NNODES 50000
#define NEDGES 800000
#define NBLK 768
#define NCHUNK 196  // ceil(50000/256) chunks per set

typedef __bf16 bf16x8 __attribute__((ext_vector_type(8)));
typedef float f32x4 __attribute__((ext_vector_type(4)));
#define MFMA(a, b, c) __builtin_amdgcn_mfma_f32_16x16x32_bf16(a, b, c, 0, 0, 0)

// LDS map (bytes)
#define OFF_A 0       // [64][192] bf16 stride 384, swizzled; [0,256) reused as H1
#define OFF_H0 24576  // [64][128] bf16 stride 256, swizzled
#define OFF_P 40960   // [64 rows][4 float2] (s,ss) partials
#define OFF_PAR 43008 // b0[128] b1[128] b2[64] gam[64] bet[64] = 448 f32
#define SMEM 44800

__device__ __forceinline__ unsigned short f2bf(float f) {
  unsigned u = __builtin_bit_cast(unsigned, f);
  u = (u + 0x7fffu + ((u >> 16) & 1u)) >> 16;
  return (unsigned short)u;
}
__device__ __forceinline__ unsigned long long pk4(f32x4 v) {
  union { unsigned short h[4]; unsigned long long u; } p;
  p.h[0] = f2bf(v[0]); p.h[1] = f2bf(v[1]); p.h[2] = f2bf(v[2]); p.h[3] = f2bf(v[3]);
  return p.u;
}
__device__ __forceinline__ int4 pk8(float4 a, float4 b) {
  union { unsigned short us[8]; int4 v; } u;
  u.us[0] = f2bf(a.x); u.us[1] = f2bf(a.y); u.us[2] = f2bf(a.z); u.us[3] = f2bf(a.w);
  u.us[4] = f2bf(b.x); u.us[5] = f2bf(b.y); u.us[6] = f2bf(b.z); u.us[7] = f2bf(b.w);
  return u.v;
}
__device__ __forceinline__ int4 ldpk(const float* p) {
  return pk8(*(const float4*)p, *(const float4*)(p + 4));
}

// EDGE: A = [xb[dst] | xb[src] | attr(g3)], residual = attr. Plain args.
// NODE: A = [aggm(g1) | aggw(g2) | x(g3)],  residual = x. (W0 pre-rotated.)
template <bool EDGE>
__global__ __launch_bounds__(512, 6) void mlp_block(
    const float* __restrict__ g1, const float* __restrict__ g2,
    const float* __restrict__ g3, const unsigned short* __restrict__ xb,
    const int* __restrict__ srcI, const int* __restrict__ dstI,
    const unsigned short* __restrict__ Wt,
    const float* __restrict__ b0, const float* __restrict__ b1,
    const float* __restrict__ b2, const float* __restrict__ gam,
    const float* __restrict__ bet, float* __restrict__ outp, int M) {
  __shared__ __align__(16) char sm[SMEM];
  const int tid = threadIdx.x, lane = tid & 63, wave = tid >> 6;
  const int lrow = lane & 15, cg = lane >> 4;
  const unsigned short* Wt0 = Wt;
  const unsigned short* Wt1 = Wt + 24576;
  const unsigned short* Wt2 = Wt + 40960;
  const int ntiles = (M + 63) >> 6;
  const int cg2 = wave & 3, rg = wave >> 2;

  // ---- stage bias/LN params into LDS ----
  for (int i = tid; i < 448; i += 512) {
    float v;
    if (i < 128) v = b0[i];
    else if (i < 256) v = b1[i - 128];
    else if (i < 320) v = b2[i - 256];
    else if (i < 384) v = gam[i - 320];
    else v = bet[i - 384];
    ((float*)(sm + OFF_PAR))[i] = v;
  }
  const float* PAR = (const float*)(sm + OFF_PAR);

  // ---- persistent weight fragments, deduped across waves ----
  bf16x8 w0f[6], w1f[4], w2f[4];
#pragma unroll
  for (int kk = 0; kk < 6; ++kk)
    w0f[kk] = *(const bf16x8*)(Wt0 + (wave * 16 + lrow) * 192 + kk * 32 + cg * 8);
#pragma unroll
  for (int kk = 0; kk < 4; ++kk)
    w1f[kk] = *(const bf16x8*)(Wt1 + (wave * 16 + lrow) * 128 + kk * 32 + cg * 8);
#pragma unroll
  for (int kk = 0; kk < 4; ++kk)
    w2f[kk] = *(const bf16x8*)(Wt2 + (cg2 * 16 + lrow) * 128 + kk * 32 + cg * 8);

  // staging map: row = (tid>>5)*4 + ((tid&31)>>3), float-octet oct = tid&7
  const int srow = (tid >> 5) * 4 + ((tid & 31) >> 3), oct = tid & 7;

  __syncthreads();  // PAR ready

  for (int t = blockIdx.x; t < ntiles; t += gridDim.x) {
    // ---- stage tile t directly (no persistent prefetch regs) ----
    {
      const int row = t * 64 + srow;
      int4 pxd, pxs, pat;
      if (EDGE) {
        const int d = dstI[row], s2 = srcI[row];
        pxd = *(const int4*)(xb + (size_t)d * 64 + oct * 8);
        pxs = *(const int4*)(xb + (size_t)s2 * 64 + oct * 8);
        pat = ldpk(g3 + (size_t)row * 64 + oct * 8);
      } else {
        const int rr = min(row, M - 1);
        pxd = ldpk(g1 + (size_t)rr * 64 + oct * 8);
        pxs = ldpk(g2 + (size_t)rr * 64 + oct * 8);
        pat = ldpk(g3 + (size_t)rr * 64 + oct * 8);
      }
      char* a0 = sm + OFF_A + srow * 384;
      const int swz = (srow & 7) << 4;
      *(int4*)(a0 + ((oct * 16) ^ swz)) = pxd;
      *(int4*)(a0 + ((128 + oct * 16) ^ swz)) = pxs;
      *(int4*)(a0 + ((256 + oct * 16) ^ swz)) = pat;
    }
    __syncthreads();  // (b) A ready
    // ---------------- L0: A[192] -> H0[128], relu ----------------
    {
      const f32x4 bb0 = *(const f32x4*)(PAR + wave * 16 + cg * 4);
#pragma unroll
      for (int rt = 0; rt < 4; ++rt) {
        const int row = rt * 16 + lrow, swz = (row & 7) << 4;
        const char* ab = sm + OFF_A + row * 384;
        f32x4 acc = {0.f, 0.f, 0.f, 0.f};
#pragma unroll
        for (int kk = 0; kk < 6; ++kk)
          acc = MFMA(w0f[kk], *(const bf16x8*)(ab + ((kk * 64 + cg * 16) ^ swz)), acc);
        f32x4 h;
#pragma unroll
        for (int q = 0; q < 4; ++q) h[q] = fmaxf(acc[q] + bb0[q], 0.f);
        *(unsigned long long*)(sm + OFF_H0 + row * 256 + ((wave * 32 + cg * 8) ^ swz)) = pk4(h);
      }
    }
    __syncthreads();  // (c) H0 ready
    // ---------------- L1: H0 -> H1 (A[0,256) overlay), relu ----------------
    {
      const f32x4 bb1 = *(const f32x4*)(PAR + 128 + wave * 16 + cg * 4);
#pragma unroll
      for (int rt = 0; rt < 4; ++rt) {
        const int row = rt * 16 + lrow, swz = (row & 7) << 4;
        const char* hb = sm + OFF_H0 + row * 256;
        f32x4 acc = {0.f, 0.f, 0.f, 0.f};
#pragma unroll
        for (int kk = 0; kk < 4; ++kk)
          acc = MFMA(w1f[kk], *(const bf16x8*)(hb + ((kk * 64 + cg * 16) ^ swz)), acc);
        f32x4 h;
#pragma unroll
        for (int q = 0; q < 4; ++q) h[q] = fmaxf(acc[q] + bb1[q], 0.f);
        *(unsigned long long*)(sm + OFF_A + row * 384 + ((wave * 32 + cg * 8) ^ swz)) = pk4(h);
      }
    }
    __syncthreads();  // (d) H1 ready
    // ---------------- L2p: H1 -> acc + bias, LN partials ----------------
    f32x4 accE[2];
    {
      const f32x4 bb2 = *(const f32x4*)(PAR + 256 + cg2 * 16 + cg * 4);
#pragma unroll
      for (int j = 0; j < 2; ++j) {
        const int row = (rg * 2 + j) * 16 + lrow, swz = (row & 7) << 4;
        const char* hb = sm + OFF_A + row * 384;
        f32x4 acc = {0.f, 0.f, 0.f, 0.f};
#pragma unroll
        for (int kk = 0; kk < 4; ++kk)
          acc = MFMA(w2f[kk], *(const bf16x8*)(hb + ((kk * 64 + cg * 16) ^ swz)), acc);
#pragma unroll
        for (int q = 0; q < 4; ++q) acc[q] += bb2[q];
        float s = acc[0] + acc[1] + acc[2] + acc[3];
        float ss = acc[0] * acc[0] + acc[1] * acc[1] + acc[2] * acc[2] + acc[3] * acc[3];
        s += __shfl_xor(s, 16, 64); s += __shfl_xor(s, 32, 64);
        ss += __shfl_xor(ss, 16, 64); ss += __shfl_xor(ss, 32, 64);
        if (cg == 0) *(float2*)(sm + OFF_P + row * 32 + cg2 * 8) = make_float2(s, ss);
        accE[j] = acc;
      }
    }
    __syncthreads();  // (e) partials ready; A region free for next stage
    // ---------------- epilogue: LN + residual(global, L2) + store ----------------
    {
      const f32x4 gv = *(const f32x4*)(PAR + 320 + cg2 * 16 + cg * 4);
      const f32x4 bv = *(const f32x4*)(PAR + 384 + cg2 * 16 + cg * 4);
#pragma unroll
      for (int j = 0; j < 2; ++j) {
        const int row = (rg * 2 + j) * 16 + lrow, gr = t * 64 + row;
        float4 p0 = *(const float4*)(sm + OFF_P + row * 32);
        float4 p1 = *(const float4*)(sm + OFF_P + row * 32 + 16);
        float s = p0.x + p0.z + p1.x + p1.z, ss = p0.y + p0.w + p1.y + p1.w;
        float mean = s * (1.f / 64.f);
        float var = fmaxf(ss * (1.f / 64.f) - mean * mean, 0.f);
        float inv = rsqrtf(var + 1e-5f);
        const int col = cg2 * 16 + cg * 4;
        const int grc = EDGE ? gr : min(gr, M - 1);
        const f32x4 r = *(const f32x4*)(g3 + (size_t)grc * 64 + col);
        f32x4 av = accE[j], o;
#pragma unroll
        for (int q = 0; q < 4; ++q) o[q] = (av[q] - mean) * inv * gv[q] + bv[q] + r[q];
        if (EDGE || gr < M) *(f32x4*)(outp + (size_t)gr * 64 + col) = o;
      }
    }
  }
}

// ---- K_agg: CSR segment-sum, both sets, 4-wide row loads per lane-group ----
__global__ __launch_bounds__(256) void agg_k(const float* __restrict__ em,
                                             const float* __restrict__ ew,
                                             const int* __restrict__ permM,
                                             const int* __restrict__ permW,
                                             const int* __restrict__ rpM,
                                             const int* __restrict__ rpW,
                                             float* __restrict__ aggm,
                                             float* __restrict__ aggw) {
  const int lane = threadIdx.x & 63;
  const int r4 = lane >> 4, cq = lane & 15;
  const int w = (blockIdx.x * 256 + threadIdx.x) >> 6;
  const int nw = gridDim.x * 4;
  for (int dd = w; dd < 2 * NNODES; dd += nw) {
    const bool s1 = dd >= NNODES;
    const int d = s1 ? dd - NNODES : dd;
    const float* oute = s1 ? ew : em;
    const int* perm = s1 ? permW : permM;
    const int* rp = s1 ? rpW : rpM;
    const int s = rp[d], e = rp[d + 1];
    f32x4 a0 = {0.f, 0.f, 0.f, 0.f}, a1 = {0.f, 0.f, 0.f, 0.f};
    f32x4 a2 = {0.f, 0.f, 0.f, 0.f}, a3 = {0.f, 0.f, 0.f, 0.f};
    int j = s + r4;
    for (; j + 12 < e; j += 16) {
      const int p0 = perm[j], p1 = perm[j + 4], p2 = perm[j + 8], p3 = perm[j + 12];
      const f32x4 v0 = *(const f32x4*)(oute + (size_t)p0 * 64 + cq * 4);
      const f32x4 v1 = *(const f32x4*)(oute + (size_t)p1 * 64 + cq * 4);
      const f32x4 v2 = *(const f32x4*)(oute + (size_t)p2 * 64 + cq * 4);
      const f32x4 v3 = *(const f32x4*)(oute + (size_t)p3 * 64 + cq * 4);
#pragma unroll
      for (int q = 0; q < 4; ++q) {
        a0[q] += v0[q]; a1[q] += v1[q]; a2[q] += v2[q]; a3[q] += v3[q];
      }
    }
    for (; j + 4 < e; j += 8) {
      const int p0 = perm[j], p1 = perm[j + 4];
      const f32x4 v0 = *(const f32x4*)(oute + (size_t)p0 * 64 + cq * 4);
      const f32x4 v1 = *(const f32x4*)(oute + (size_t)p1 * 64 + cq * 4);
#pragma unroll
      for (int q = 0; q < 4; ++q) { a0[q] += v0[q]; a1[q] += v1[q]; }
    }
    if (j < e) {
      const f32x4 v0 = *(const f32x4*)(oute + (size_t)perm[j] * 64 + cq * 4);
#pragma unroll
      for (int q = 0; q < 4; ++q) a0[q] += v0[q];
    }
#pragma unroll
    for (int q = 0; q < 4; ++q) {
      a0[q] += a1[q] + a2[q] + a3[q];
      a0[q] += __shfl_xor(a0[q], 16, 64);
      a0[q] += __shfl_xor(a0[q], 32, 64);
    }
    float* agg = s1 ? aggw : aggm;
    if (r4 == 0) *(f32x4*)(agg + (size_t)d * 64 + cq * 4) = a0;
  }
}

// ---- prep: weights -> bf16 [out][in] (upd-W0 rotated); x -> bf16 table ----
struct PrepArgs { const float* w[9]; unsigned short* wt[3]; };

__global__ void prep_w(PrepArgs pa) {
  int i = blockIdx.x * 256 + threadIdx.x;
  if (i >= 3 * 49152) return;
  int mlp = i / 49152;
  int rem = i - mlp * 49152;
  int mat, off, K, N;
  if (rem < 24576)      { mat = 0; off = 0;     K = 192; N = 128; }
  else if (rem < 40960) { mat = 1; off = 24576; K = 128; N = 128; }
  else                  { mat = 2; off = 40960; K = 128; N = 64;  }
  int local = rem - off;
  int n = local / K, k = local - n * K;
  if (mlp == 2 && mat == 0) k = (k + 64) % 192;  // node concat [aggm|aggw|x]
  pa.wt[mlp][rem] = f2bf(pa.w[mlp * 3 + mat][k * N + n]);
}

__global__ void prep_x(const float* __restrict__ x, unsigned short* __restrict__ xb) {
  int i = blockIdx.x * 256 + threadIdx.x;
  if (i < NNODES * 8) *(int4*)(xb + (size_t)i * 8) = ldpk(x + (size_t)i * 8);
}

__global__ void zero_f4(float4* p, int n) {
  int i = blockIdx.x * blockDim.x + threadIdx.x;
  if (i < n) p[i] = make_float4(0.f, 0.f, 0.f, 0.f);
}

// ---- counting sort by dst: hist -> parallel chunk scan -> scatter ----
__global__ void hist_k(const int* __restrict__ dM, const int* __restrict__ dW,
                       int* __restrict__ curM, int* __restrict__ curW, int E) {
  int i = blockIdx.x * 256 + threadIdx.x;
  if (i < E) {
    atomicAdd(curM + dM[i], 1);
    atomicAdd(curW + dW[i], 1);
  }
}

__global__ __launch_bounds__(64) void csum_k(const int* __restrict__ curM,
                                             const int* __restrict__ curW,
                                             int* __restrict__ csum) {
  const int c = blockIdx.x, set = c >= NCHUNK, c0 = c - set * NCHUNK;
  const int* cnt = set ? curW : curM;
  const int lane = threadIdx.x;
  const int base = c0 * 256 + lane * 4;
  int s = 0;
  if (base + 3 < NNODES) {
    int4 v = *(const int4*)(cnt + base);
    s = v.x + v.y + v.z + v.w;
  } else {
    for (int k = 0; k < 4; ++k) if (base + k < NNODES) s += cnt[base + k];
  }
#pragma unroll
  for (int off = 1; off < 64; off <<= 1) s += __shfl_xor(s, off, 64);
  if (lane == 0) csum[c] = s;
}

__global__ __launch_bounds__(512) void cscan_k(const int* __restrict__ csum,
                                               int* __restrict__ cbase) {
  __shared__ int buf[512];
  const int tid = threadIdx.x;
  buf[tid] = (tid < 2 * NCHUNK) ? csum[tid] : 0;
  __syncthreads();
  for (int off = 1; off < 512; off <<= 1) {
    int nv = (tid >= off) ? buf[tid - off] : 0;
    __syncthreads();
    buf[tid] += nv;
    __syncthreads();
  }
  if (tid < 2 * NCHUNK) {
    const int set = tid >= NCHUNK;
    int excl = tid ? buf[tid - 1] : 0;
    if (set) excl -= buf[NCHUNK - 1];
    cbase[tid] = excl;
  }
}

__global__ __launch_bounds__(64) void rp_k(int* __restrict__ curM, int* __restrict__ curW,
                                           const int* __restrict__ cbase,
                                           int* __restrict__ rpM, int* __restrict__ rpW) {
  const int c = blockIdx.x, set = c >= NCHUNK, c0 = c - set * NCHUNK;
  int* cnt = set ? curW : curM;
  int* rp = set ? rpW : rpM;
  const int lane = threadIdx.x;
  const int idx = c0 * 256 + lane * 4;
  int v[4];
#pragma unroll
  for (int k = 0; k < 4; ++k) v[k] = (idx + k < NNODES) ? cnt[idx + k] : 0;
  const int ls = v[0] + v[1] + v[2] + v[3];
  int ex = ls;
#pragma unroll
  for (int off = 1; off < 64; off <<= 1) {
    int nv = __shfl_up(ex, off, 64);
    if (lane >= off) ex += nv;
  }
  int run = cbase[c] + (ex - ls);
#pragma unroll
  for (int k = 0; k < 4; ++k) {
    if (idx + k < NNODES) {
      rp[idx + k] = run;
      cnt[idx + k] = run;
      run += v[k];
    }
  }
  if (c0 == 0 && lane == 0) rp[NNODES] = NEDGES;
}

__global__ void scatter_k(const int* __restrict__ dM, const int* __restrict__ dW,
                          int* __restrict__ curM, int* __restrict__ curW,
                          int* __restrict__ permM, int* __restrict__ permW, int E) {
  int i = blockIdx.x * 256 + threadIdx.x;
  if (i < E) {
    int p = atomicAdd(curM + dM[i], 1);
    permM[p] = i;
    p = atomicAdd(curW + dW[i], 1);
    permW[p] = i;
  }
}

extern "C" void kernel_launch(void* const* d_in, const int* in_sizes, int n_in,
                              void* d_out, int out_size, void* d_ws, size_t ws_size,
                              hipStream_t stream) {
  const float* x      = (const float*)d_in[0];
  const int*   meIdx  = (const int*)d_in[1];
  const float* meAttr = (const float*)d_in[2];
  const int*   weIdx  = (const int*)d_in[3];
  const float* weAttr = (const float*)d_in[4];

  float* out_x  = (float*)d_out;
  float* out_em = out_x + (size_t)NNODES * 64;
  float* out_ew = out_em + (size_t)NEDGES * 64;

  char* ws = (char*)d_ws;
  unsigned short* WtM = (unsigned short*)ws;                    // 3 x 98304
  unsigned short* WtW = (unsigned short*)(ws + 98304);
  unsigned short* WtU = (unsigned short*)(ws + 196608);
  unsigned short* xb  = (unsigned short*)(ws + 294912);         // 6.4 MB
  float* aggm = (float*)(ws + 6694912);                         // 12.8 MB
  float* aggw = (float*)(ws + 19494912);                        // 12.8 MB
  char* p = ws + 32294912;
  int* curM  = (int*)p;                                         // 200 KB
  int* curW  = curM + NNODES;                                   // 200 KB
  int* rpM   = (int*)(p + 400000);                              // 50016 ints
  int* rpW   = rpM + 50016;
  int* permM = rpW + 50016;                                     // 3.2 MB
  int* permW = permM + NEDGES;                                  // 3.2 MB
  int* csum  = permW + NEDGES;                                  // 392 ints
  int* cbase = csum + 512;                                      // end ~39.5 MB

  zero_f4<<<dim3(98), dim3(256), 0, stream>>>((float4*)curM, 25000);

  PrepArgs pa;
  for (int m = 0; m < 3; ++m)
    for (int l = 0; l < 3; ++l)
      pa.w[m * 3 + l] = (const float*)d_in[5 + m * 8 + l * 2];
  pa.wt[0] = WtM; pa.wt[1] = WtW; pa.wt[2] = WtU;
  prep_w<<<dim3(576), dim3(256), 0, stream>>>(pa);
  prep_x<<<dim3(1563), dim3(256), 0, stream>>>(x, xb);

  hist_k<<<dim3(3125), dim3(256), 0, stream>>>(meIdx + NEDGES, weIdx + NEDGES, curM, curW, NEDGES);
  csum_k<<<dim3(2 * NCHUNK), dim3(64), 0, stream>>>(curM, curW, csum);
  cscan_k<<<dim3(1), dim3(512), 0, stream>>>(csum, cbase);
  rp_k<<<dim3(2 * NCHUNK), dim3(64), 0, stream>>>(curM, curW, cbase, rpM, rpW);
  scatter_k<<<dim3(3125), dim3(256), 0, stream>>>(meIdx + NEDGES, weIdx + NEDGES,
                                                  curM, curW, permM, permW, NEDGES);

  // edge MLPs (original order; x_i = x[dst], x_j = x[src])
  mlp_block<true><<<dim3(NBLK), dim3(512), 0, stream>>>(
      nullptr, nullptr, meAttr, xb, meIdx, meIdx + NEDGES, WtM,
      (const float*)d_in[6], (const float*)d_in[8], (const float*)d_in[10],
      (const float*)d_in[11], (const float*)d_in[12],
      out_em, NEDGES);
  mlp_block<true><<<dim3(NBLK), dim3(512), 0, stream>>>(
      nullptr, nullptr, weAttr, xb, weIdx, weIdx + NEDGES, WtW,
      (const float*)d_in[14], (const float*)d_in[16], (const float*)d_in[18],
      (const float*)d_in[19], (const float*)d_in[20],
      out_ew, NEDGES);

  // merged CSR segment sums (4-wide ILP)
  agg_k<<<dim3(4096), dim3(256), 0, stream>>>(out_em, out_ew, permM, permW, rpM, rpW, aggm, aggw);

  // node update: A = [aggm | aggw | x], residual = x
  mlp_block<false><<<dim3(NBLK), dim3(512), 0, stream>>>(
      aggm, aggw, x, nullptr, nullptr, nullptr, WtU,
      (const float*)d_in[22], (const float*)d_in[24], (const float*)d_in[26],
      (const float*)d_in[27], (const float*)d_in[28],
      out_x, NNODES);
}

// Round 16
// 1005.025 us; speedup vs baseline: 1.1778x; 1.1778x over previous
//
#include <hip/hip_runtime.h>

// InteractionNetwork — decomposed (R13 structure + 3-blocks/CU):
//   prep_x : x -> bf16 table xb (6.4 MB): edge gathers read 128B rows.
//   K_mlp  : edge (two single-set dispatches) / node MLP+LN.
//            Weight frags are loaded PER PHASE from global (L2-resident) with
//            an anti-LICM asm barrier — removes the 56-reg persistent state
//            that forced 2 blocks/CU (R15 showed the cap alone just spills).
//            __launch_bounds__(512,6) -> 3 blocks/CU (LDS 3x44.8=134KB).
//   K_agg  : CSR segment-sum, both sets, 4-wide row loads per lane-group.
//   sort   : hist -> parallel chunk-scan -> scatter(perm).
// MLP: OUT^T = W^T * X^T, activations through XOR-swizzled LDS, 4 barriers/tile.

#define NNODES 50000
#define NEDGES 800000
#define NBLK 768
#define NCHUNK 196  // ceil(50000/256) chunks per set

typedef __bf16 bf16x8 __attribute__((ext_vector_type(8)));
typedef float f32x4 __attribute__((ext_vector_type(4)));
#define MFMA(a, b, c) __builtin_amdgcn_mfma_f32_16x16x32_bf16(a, b, c, 0, 0, 0)

// LDS map (bytes)
#define OFF_A 0       // [64][192] bf16 stride 384, swizzled; [0,256) reused as H1
#define OFF_H0 24576  // [64][128] bf16 stride 256, swizzled
#define OFF_P 40960   // [64 rows][4 float2] (s,ss) partials
#define OFF_PAR 43008 // b0[128] b1[128] b2[64] gam[64] bet[64] = 448 f32
#define SMEM 44800

__device__ __forceinline__ unsigned short f2bf(float f) {
  unsigned u = __builtin_bit_cast(unsigned, f);
  u = (u + 0x7fffu + ((u >> 16) & 1u)) >> 16;
  return (unsigned short)u;
}
__device__ __forceinline__ unsigned long long pk4(f32x4 v) {
  union { unsigned short h[4]; unsigned long long u; } p;
  p.h[0] = f2bf(v[0]); p.h[1] = f2bf(v[1]); p.h[2] = f2bf(v[2]); p.h[3] = f2bf(v[3]);
  return p.u;
}
__device__ __forceinline__ int4 pk8(float4 a, float4 b) {
  union { unsigned short us[8]; int4 v; } u;
  u.us[0] = f2bf(a.x); u.us[1] = f2bf(a.y); u.us[2] = f2bf(a.z); u.us[3] = f2bf(a.w);
  u.us[4] = f2bf(b.x); u.us[5] = f2bf(b.y); u.us[6] = f2bf(b.z); u.us[7] = f2bf(b.w);
  return u.v;
}
__device__ __forceinline__ int4 ldpk(const float* p) {
  return pk8(*(const float4*)p, *(const float4*)(p + 4));
}

// EDGE: A = [xb[dst] | xb[src] | attr(g3)], residual = attr. Plain args.
// NODE: A = [aggm(g1) | aggw(g2) | x(g3)],  residual = x. (W0 pre-rotated.)
template <bool EDGE>
__global__ __launch_bounds__(512, 6) void mlp_block(
    const float* __restrict__ g1, const float* __restrict__ g2,
    const float* __restrict__ g3, const unsigned short* __restrict__ xb,
    const int* __restrict__ srcI, const int* __restrict__ dstI,
    const unsigned short* __restrict__ Wt,
    const float* __restrict__ b0, const float* __restrict__ b1,
    const float* __restrict__ b2, const float* __restrict__ gam,
    const float* __restrict__ bet, float* __restrict__ outp, int M) {
  __shared__ __align__(16) char sm[SMEM];
  const int tid = threadIdx.x, lane = tid & 63, wave = tid >> 6;
  const int lrow = lane & 15, cg = lane >> 4;
  const int ntiles = (M + 63) >> 6;
  const int cg2 = wave & 3, rg = wave >> 2;

  // ---- stage bias/LN params into LDS ----
  for (int i = tid; i < 448; i += 512) {
    float v;
    if (i < 128) v = b0[i];
    else if (i < 256) v = b1[i - 128];
    else if (i < 320) v = b2[i - 256];
    else if (i < 384) v = gam[i - 320];
    else v = bet[i - 384];
    ((float*)(sm + OFF_PAR))[i] = v;
  }
  const float* PAR = (const float*)(sm + OFF_PAR);

  // staging map: row = (tid>>5)*4 + ((tid&31)>>3), float-octet oct = tid&7
  const int srow = (tid >> 5) * 4 + ((tid & 31) >> 3), oct = tid & 7;

  int4 pxd, pxs, pat;
  auto LOADT = [&](int tt) {
    const int row = tt * 64 + srow;
    if (EDGE) {
      const int d = dstI[row], s2 = srcI[row];
      pxd = *(const int4*)(xb + (size_t)d * 64 + oct * 8);
      pxs = *(const int4*)(xb + (size_t)s2 * 64 + oct * 8);
      pat = ldpk(g3 + (size_t)row * 64 + oct * 8);
    } else {
      const int rr = min(row, M - 1);
      pxd = ldpk(g1 + (size_t)rr * 64 + oct * 8);
      pxs = ldpk(g2 + (size_t)rr * 64 + oct * 8);
      pat = ldpk(g3 + (size_t)rr * 64 + oct * 8);
    }
  };
  auto STAGE = [&]() {
    char* a0 = sm + OFF_A + srow * 384;
    const int swz = (srow & 7) << 4;
    *(int4*)(a0 + ((oct * 16) ^ swz)) = pxd;
    *(int4*)(a0 + ((128 + oct * 16) ^ swz)) = pxs;
    *(int4*)(a0 + ((256 + oct * 16) ^ swz)) = pat;
  };

  int t = blockIdx.x;
  if (t >= ntiles) return;
  LOADT(t);
  STAGE();

  for (; t < ntiles; t += NBLK) {
    const int tn = t + NBLK;
    const bool more = tn < ntiles;
    __syncthreads();  // (a) A(t) + PAR visible
    if (more) LOADT(tn);  // next-tile global loads ride under the MFMA phases
    // ---------------- L0: A[192] -> H0[128], relu ----------------
    {
      // per-phase weight frags; asm blinds LICM so they are NOT persistent
      const unsigned short* w0p = Wt;
      asm volatile("" : "+s"(w0p));
      bf16x8 w0f[6];
#pragma unroll
      for (int kk = 0; kk < 6; ++kk)
        w0f[kk] = *(const bf16x8*)(w0p + (wave * 16 + lrow) * 192 + kk * 32 + cg * 8);
      const f32x4 bb0 = *(const f32x4*)(PAR + wave * 16 + cg * 4);
#pragma unroll
      for (int rt = 0; rt < 4; ++rt) {
        const int row = rt * 16 + lrow, swz = (row & 7) << 4;
        const char* ab = sm + OFF_A + row * 384;
        f32x4 acc = {0.f, 0.f, 0.f, 0.f};
#pragma unroll
        for (int kk = 0; kk < 6; ++kk)
          acc = MFMA(w0f[kk], *(const bf16x8*)(ab + ((kk * 64 + cg * 16) ^ swz)), acc);
        f32x4 h;
#pragma unroll
        for (int q = 0; q < 4; ++q) h[q] = fmaxf(acc[q] + bb0[q], 0.f);
        *(unsigned long long*)(sm + OFF_H0 + row * 256 + ((wave * 32 + cg * 8) ^ swz)) = pk4(h);
      }
    }
    __syncthreads();  // (c) H0 ready
    // ---------------- L1: H0 -> H1 (A[0,256) overlay), relu ----------------
    {
      const unsigned short* w1p = Wt + 24576;
      asm volatile("" : "+s"(w1p));
      bf16x8 w1f[4];
#pragma unroll
      for (int kk = 0; kk < 4; ++kk)
        w1f[kk] = *(const bf16x8*)(w1p + (wave * 16 + lrow) * 128 + kk * 32 + cg * 8);
      const f32x4 bb1 = *(const f32x4*)(PAR + 128 + wave * 16 + cg * 4);
#pragma unroll
      for (int rt = 0; rt < 4; ++rt) {
        const int row = rt * 16 + lrow, swz = (row & 7) << 4;
        const char* hb = sm + OFF_H0 + row * 256;
        f32x4 acc = {0.f, 0.f, 0.f, 0.f};
#pragma unroll
        for (int kk = 0; kk < 4; ++kk)
          acc = MFMA(w1f[kk], *(const bf16x8*)(hb + ((kk * 64 + cg * 16) ^ swz)), acc);
        f32x4 h;
#pragma unroll
        for (int q = 0; q < 4; ++q) h[q] = fmaxf(acc[q] + bb1[q], 0.f);
        *(unsigned long long*)(sm + OFF_A + row * 384 + ((wave * 32 + cg * 8) ^ swz)) = pk4(h);
      }
    }
    __syncthreads();  // (d) H1 ready
    // ---------------- L2p: H1 -> acc + bias, LN partials ----------------
    f32x4 accE[2];
    {
      const unsigned short* w2p = Wt + 40960;
      asm volatile("" : "+s"(w2p));
      bf16x8 w2f[4];
#pragma unroll
      for (int kk = 0; kk < 4; ++kk)
        w2f[kk] = *(const bf16x8*)(w2p + (cg2 * 16 + lrow) * 128 + kk * 32 + cg * 8);
      const f32x4 bb2 = *(const f32x4*)(PAR + 256 + cg2 * 16 + cg * 4);
#pragma unroll
      for (int j = 0; j < 2; ++j) {
        const int row = (rg * 2 + j) * 16 + lrow, swz = (row & 7) << 4;
        const char* hb = sm + OFF_A + row * 384;
        f32x4 acc = {0.f, 0.f, 0.f, 0.f};
#pragma unroll
        for (int kk = 0; kk < 4; ++kk)
          acc = MFMA(w2f[kk], *(const bf16x8*)(hb + ((kk * 64 + cg * 16) ^ swz)), acc);
#pragma unroll
        for (int q = 0; q < 4; ++q) acc[q] += bb2[q];
        float s = acc[0] + acc[1] + acc[2] + acc[3];
        float ss = acc[0] * acc[0] + acc[1] * acc[1] + acc[2] * acc[2] + acc[3] * acc[3];
        s += __shfl_xor(s, 16, 64); s += __shfl_xor(s, 32, 64);
        ss += __shfl_xor(ss, 16, 64); ss += __shfl_xor(ss, 32, 64);
        if (cg == 0) *(float2*)(sm + OFF_P + row * 32 + cg2 * 8) = make_float2(s, ss);
        accE[j] = acc;
      }
    }
    __syncthreads();  // (e) partials ready; A free for next stage
    // ---------------- epilogue: LN + residual(global, L2) + store ----------------
    {
      const f32x4 gv = *(const f32x4*)(PAR + 320 + cg2 * 16 + cg * 4);
      const f32x4 bv = *(const f32x4*)(PAR + 384 + cg2 * 16 + cg * 4);
#pragma unroll
      for (int j = 0; j < 2; ++j) {
        const int row = (rg * 2 + j) * 16 + lrow, gr = t * 64 + row;
        float4 p0 = *(const float4*)(sm + OFF_P + row * 32);
        float4 p1 = *(const float4*)(sm + OFF_P + row * 32 + 16);
        float s = p0.x + p0.z + p1.x + p1.z, ss = p0.y + p0.w + p1.y + p1.w;
        float mean = s * (1.f / 64.f);
        float var = fmaxf(ss * (1.f / 64.f) - mean * mean, 0.f);
        float inv = rsqrtf(var + 1e-5f);
        const int col = cg2 * 16 + cg * 4;
        const int grc = EDGE ? gr : min(gr, M - 1);
        const f32x4 r = *(const f32x4*)(g3 + (size_t)grc * 64 + col);
        f32x4 av = accE[j], o;
#pragma unroll
        for (int q = 0; q < 4; ++q) o[q] = (av[q] - mean) * inv * gv[q] + bv[q] + r[q];
        if (EDGE || gr < M) *(f32x4*)(outp + (size_t)gr * 64 + col) = o;
      }
    }
    if (more) STAGE();
  }
}

// ---- K_agg: CSR segment-sum, both sets, 4-wide row loads per lane-group ----
__global__ __launch_bounds__(256) void agg_k(const float* __restrict__ em,
                                             const float* __restrict__ ew,
                                             const int* __restrict__ permM,
                                             const int* __restrict__ permW,
                                             const int* __restrict__ rpM,
                                             const int* __restrict__ rpW,
                                             float* __restrict__ aggm,
                                             float* __restrict__ aggw) {
  const int lane = threadIdx.x & 63;
  const int r4 = lane >> 4, cq = lane & 15;
  const int w = (blockIdx.x * 256 + threadIdx.x) >> 6;
  const int nw = gridDim.x * 4;
  for (int dd = w; dd < 2 * NNODES; dd += nw) {
    const bool s1 = dd >= NNODES;
    const int d = s1 ? dd - NNODES : dd;
    const float* oute = s1 ? ew : em;
    const int* perm = s1 ? permW : permM;
    const int* rp = s1 ? rpW : rpM;
    const int s = rp[d], e = rp[d + 1];
    f32x4 a0 = {0.f, 0.f, 0.f, 0.f}, a1 = {0.f, 0.f, 0.f, 0.f};
    f32x4 a2 = {0.f, 0.f, 0.f, 0.f}, a3 = {0.f, 0.f, 0.f, 0.f};
    int j = s + r4;
    for (; j + 12 < e; j += 16) {
      const int p0 = perm[j], p1 = perm[j + 4], p2 = perm[j + 8], p3 = perm[j + 12];
      const f32x4 v0 = *(const f32x4*)(oute + (size_t)p0 * 64 + cq * 4);
      const f32x4 v1 = *(const f32x4*)(oute + (size_t)p1 * 64 + cq * 4);
      const f32x4 v2 = *(const f32x4*)(oute + (size_t)p2 * 64 + cq * 4);
      const f32x4 v3 = *(const f32x4*)(oute + (size_t)p3 * 64 + cq * 4);
#pragma unroll
      for (int q = 0; q < 4; ++q) {
        a0[q] += v0[q]; a1[q] += v1[q]; a2[q] += v2[q]; a3[q] += v3[q];
      }
    }
    for (; j + 4 < e; j += 8) {
      const int p0 = perm[j], p1 = perm[j + 4];
      const f32x4 v0 = *(const f32x4*)(oute + (size_t)p0 * 64 + cq * 4);
      const f32x4 v1 = *(const f32x4*)(oute + (size_t)p1 * 64 + cq * 4);
#pragma unroll
      for (int q = 0; q < 4; ++q) { a0[q] += v0[q]; a1[q] += v1[q]; }
    }
    if (j < e) {
      const f32x4 v0 = *(const f32x4*)(oute + (size_t)perm[j] * 64 + cq * 4);
#pragma unroll
      for (int q = 0; q < 4; ++q) a0[q] += v0[q];
    }
#pragma unroll
    for (int q = 0; q < 4; ++q) {
      a0[q] += a1[q] + a2[q] + a3[q];
      a0[q] += __shfl_xor(a0[q], 16, 64);
      a0[q] += __shfl_xor(a0[q], 32, 64);
    }
    float* agg = s1 ? aggw : aggm;
    if (r4 == 0) *(f32x4*)(agg + (size_t)d * 64 + cq * 4) = a0;
  }
}

// ---- prep: weights -> bf16 [out][in] (upd-W0 rotated); x -> bf16 table ----
struct PrepArgs { const float* w[9]; unsigned short* wt[3]; };

__global__ void prep_w(PrepArgs pa) {
  int i = blockIdx.x * 256 + threadIdx.x;
  if (i >= 3 * 49152) return;
  int mlp = i / 49152;
  int rem = i - mlp * 49152;
  int mat, off, K, N;
  if (rem < 24576)      { mat = 0; off = 0;     K = 192; N = 128; }
  else if (rem < 40960) { mat = 1; off = 24576; K = 128; N = 128; }
  else                  { mat = 2; off = 40960; K = 128; N = 64;  }
  int local = rem - off;
  int n = local / K, k = local - n * K;
  if (mlp == 2 && mat == 0) k = (k + 64) % 192;  // node concat [aggm|aggw|x]
  pa.wt[mlp][rem] = f2bf(pa.w[mlp * 3 + mat][k * N + n]);
}

__global__ void prep_x(const float* __restrict__ x, unsigned short* __restrict__ xb) {
  int i = blockIdx.x * 256 + threadIdx.x;
  if (i < NNODES * 8) *(int4*)(xb + (size_t)i * 8) = ldpk(x + (size_t)i * 8);
}

__global__ void zero_f4(float4* p, int n) {
  int i = blockIdx.x * blockDim.x + threadIdx.x;
  if (i < n) p[i] = make_float4(0.f, 0.f, 0.f, 0.f);
}

// ---- counting sort by dst: hist -> parallel chunk scan -> scatter ----
__global__ void hist_k(const int* __restrict__ dM, const int* __restrict__ dW,
                       int* __restrict__ curM, int* __restrict__ curW, int E) {
  int i = blockIdx.x * 256 + threadIdx.x;
  if (i < E) {
    atomicAdd(curM + dM[i], 1);
    atomicAdd(curW + dW[i], 1);
  }
}

__global__ __launch_bounds__(64) void csum_k(const int* __restrict__ curM,
                                             const int* __restrict__ curW,
                                             int* __restrict__ csum) {
  const int c = blockIdx.x, set = c >= NCHUNK, c0 = c - set * NCHUNK;
  const int* cnt = set ? curW : curM;
  const int lane = threadIdx.x;
  const int base = c0 * 256 + lane * 4;
  int s = 0;
  if (base + 3 < NNODES) {
    int4 v = *(const int4*)(cnt + base);
    s = v.x + v.y + v.z + v.w;
  } else {
    for (int k = 0; k < 4; ++k) if (base + k < NNODES) s += cnt[base + k];
  }
#pragma unroll
  for (int off = 1; off < 64; off <<= 1) s += __shfl_xor(s, off, 64);
  if (lane == 0) csum[c] = s;
}

__global__ __launch_bounds__(512) void cscan_k(const int* __restrict__ csum,
                                               int* __restrict__ cbase) {
  __shared__ int buf[512];
  const int tid = threadIdx.x;
  buf[tid] = (tid < 2 * NCHUNK) ? csum[tid] : 0;
  __syncthreads();
  for (int off = 1; off < 512; off <<= 1) {
    int nv = (tid >= off) ? buf[tid - off] : 0;
    __syncthreads();
    buf[tid] += nv;
    __syncthreads();
  }
  if (tid < 2 * NCHUNK) {
    const int set = tid >= NCHUNK;
    int excl = tid ? buf[tid - 1] : 0;
    if (set) excl -= buf[NCHUNK - 1];
    cbase[tid] = excl;
  }
}

__global__ __launch_bounds__(64) void rp_k(int* __restrict__ curM, int* __restrict__ curW,
                                           const int* __restrict__ cbase,
                                           int* __restrict__ rpM, int* __restrict__ rpW) {
  const int c = blockIdx.x, set = c >= NCHUNK, c0 = c - set * NCHUNK;
  int* cnt = set ? curW : curM;
  int* rp = set ? rpW : rpM;
  const int lane = threadIdx.x;
  const int idx = c0 * 256 + lane * 4;
  int v[4];
#pragma unroll
  for (int k = 0; k < 4; ++k) v[k] = (idx + k < NNODES) ? cnt[idx + k] : 0;
  const int ls = v[0] + v[1] + v[2] + v[3];
  int ex = ls;
#pragma unroll
  for (int off = 1; off < 64; off <<= 1) {
    int nv = __shfl_up(ex, off, 64);
    if (lane >= off) ex += nv;
  }
  int run = cbase[c] + (ex - ls);
#pragma unroll
  for (int k = 0; k < 4; ++k) {
    if (idx + k < NNODES) {
      rp[idx + k] = run;
      cnt[idx + k] = run;
      run += v[k];
    }
  }
  if (c0 == 0 && lane == 0) rp[NNODES] = NEDGES;
}

__global__ void scatter_k(const int* __restrict__ dM, const int* __restrict__ dW,
                          int* __restrict__ curM, int* __restrict__ curW,
                          int* __restrict__ permM, int* __restrict__ permW, int E) {
  int i = blockIdx.x * 256 + threadIdx.x;
  if (i < E) {
    int p = atomicAdd(curM + dM[i], 1);
    permM[p] = i;
    p = atomicAdd(curW + dW[i], 1);
    permW[p] = i;
  }
}

extern "C" void kernel_launch(void* const* d_in, const int* in_sizes, int n_in,
                              void* d_out, int out_size, void* d_ws, size_t ws_size,
                              hipStream_t stream) {
  const float* x      = (const float*)d_in[0];
  const int*   meIdx  = (const int*)d_in[1];
  const float* meAttr = (const float*)d_in[2];
  const int*   weIdx  = (const int*)d_in[3];
  const float* weAttr = (const float*)d_in[4];

  float* out_x  = (float*)d_out;
  float* out_em = out_x + (size_t)NNODES * 64;
  float* out_ew = out_em + (size_t)NEDGES * 64;

  char* ws = (char*)d_ws;
  unsigned short* WtM = (unsigned short*)ws;                    // 3 x 98304
  unsigned short* WtW = (unsigned short*)(ws + 98304);
  unsigned short* WtU = (unsigned short*)(ws + 196608);
  unsigned short* xb  = (unsigned short*)(ws + 294912);         // 6.4 MB
  float* aggm = (float*)(ws + 6694912);                         // 12.8 MB
  float* aggw = (float*)(ws + 19494912);                        // 12.8 MB
  char* p = ws + 32294912;
  int* curM  = (int*)p;                                         // 200 KB
  int* curW  = curM + NNODES;                                   // 200 KB
  int* rpM   = (int*)(p + 400000);                              // 50016 ints
  int* rpW   = rpM + 50016;
  int* permM = rpW + 50016;                                     // 3.2 MB
  int* permW = permM + NEDGES;                                  // 3.2 MB
  int* csum  = permW + NEDGES;                                  // 392 ints
  int* cbase = csum + 512;                                      // end ~39.5 MB

  zero_f4<<<dim3(98), dim3(256), 0, stream>>>((float4*)curM, 25000);

  PrepArgs pa;
  for (int m = 0; m < 3; ++m)
    for (int l = 0; l < 3; ++l)
      pa.w[m * 3 + l] = (const float*)d_in[5 + m * 8 + l * 2];
  pa.wt[0] = WtM; pa.wt[1] = WtW; pa.wt[2] = WtU;
  prep_w<<<dim3(576), dim3(256), 0, stream>>>(pa);
  prep_x<<<dim3(1563), dim3(256), 0, stream>>>(x, xb);

  hist_k<<<dim3(3125), dim3(256), 0, stream>>>(meIdx + NEDGES, weIdx + NEDGES, curM, curW, NEDGES);
  csum_k<<<dim3(2 * NCHUNK), dim3(64), 0, stream>>>(curM, curW, csum);
  cscan_k<<<dim3(1), dim3(512), 0, stream>>>(csum, cbase);
  rp_k<<<dim3(2 * NCHUNK), dim3(64), 0, stream>>>(curM, curW, cbase, rpM, rpW);
  scatter_k<<<dim3(3125), dim3(256), 0, stream>>>(meIdx + NEDGES, weIdx + NEDGES,
                                                  curM, curW, permM, permW, NEDGES);

  // edge MLPs (original order; x_i = x[dst], x_j = x[src])
  mlp_block<true><<<dim3(NBLK), dim3(512), 0, stream>>>(
      nullptr, nullptr, meAttr, xb, meIdx, meIdx + NEDGES, WtM,
      (const float*)d_in[6], (const float*)d_in[8], (const float*)d_in[10],
      (const float*)d_in[11], (const float*)d_in[12],
      out_em, NEDGES);
  mlp_block<true><<<dim3(NBLK), dim3(512), 0, stream>>>(
      nullptr, nullptr, weAttr, xb, weIdx, weIdx + NEDGES, WtW,
      (const float*)d_in[14], (const float*)d_in[16], (const float*)d_in[18],
      (const float*)d_in[19], (const float*)d_in[20],
      out_ew, NEDGES);

  // merged CSR segment sums (4-wide ILP)
  agg_k<<<dim3(4096), dim3(256), 0, stream>>>(out_em, out_ew, permM, permW, rpM, rpW, aggm, aggw);

  // node update: A = [aggm | aggw | x], residual = x
  mlp_block<false><<<dim3(NBLK), dim3(512), 0, stream>>>(
      aggm, aggw, x, nullptr, nullptr, nullptr, WtU,
      (const float*)d_in[22], (const float*)d_in[24], (const float*)d_in[26],
      (const float*)d_in[27], (const float*)d_in[28],
      out_x, NNODES);
}

// Round 17
// 752.879 us; speedup vs baseline: 1.5723x; 1.3349x over previous
//
#include <hip/hip_runtime.h>

// InteractionNetwork — FINAL (R13/R10 configuration, best measured: ~750 µs).
//   prep_x : x -> bf16 table xb (6.4 MB): edge gathers read 128B rows.
//   K_mlp  : edge (two single-set dispatches, original order, plain args)
//            / node MLP+LN, no atomics, direct coalesced stores.
//            Persistent deduped weight frags in regs; 2 blocks/CU (register
//            wall — R15/R16 proved 3 blocks/CU variants spill or serialize).
//   K_agg  : CSR segment-sum, both sets, 4-wide row loads per lane-group.
//   sort   : hist -> parallel chunk-scan -> scatter(perm).
// MLP: OUT^T = W^T * X^T, weight frags persistent+deduped in regs, activations
// through XOR-swizzled LDS, 4 barriers/tile, residual re-read from global (L2).

#define NNODES 50000
#define NEDGES 800000
#define NBLK 512
#define NCHUNK 196  // ceil(50000/256) chunks per set

typedef __bf16 bf16x8 __attribute__((ext_vector_type(8)));
typedef float f32x4 __attribute__((ext_vector_type(4)));
#define MFMA(a, b, c) __builtin_amdgcn_mfma_f32_16x16x32_bf16(a, b, c, 0, 0, 0)

// LDS map (bytes)
#define OFF_A 0       // [64][192] bf16 stride 384, swizzled; [0,256) reused as H1
#define OFF_H0 24576  // [64][128] bf16 stride 256, swizzled
#define OFF_P 40960   // [64 rows][4 float2] (s,ss) partials
#define OFF_PAR 43008 // b0[128] b1[128] b2[64] gam[64] bet[64] = 448 f32
#define SMEM 44800

__device__ __forceinline__ unsigned short f2bf(float f) {
  unsigned u = __builtin_bit_cast(unsigned, f);
  u = (u + 0x7fffu + ((u >> 16) & 1u)) >> 16;
  return (unsigned short)u;
}
__device__ __forceinline__ unsigned long long pk4(f32x4 v) {
  union { unsigned short h[4]; unsigned long long u; } p;
  p.h[0] = f2bf(v[0]); p.h[1] = f2bf(v[1]); p.h[2] = f2bf(v[2]); p.h[3] = f2bf(v[3]);
  return p.u;
}
__device__ __forceinline__ int4 pk8(float4 a, float4 b) {
  union { unsigned short us[8]; int4 v; } u;
  u.us[0] = f2bf(a.x); u.us[1] = f2bf(a.y); u.us[2] = f2bf(a.z); u.us[3] = f2bf(a.w);
  u.us[4] = f2bf(b.x); u.us[5] = f2bf(b.y); u.us[6] = f2bf(b.z); u.us[7] = f2bf(b.w);
  return u.v;
}
__device__ __forceinline__ int4 ldpk(const float* p) {
  return pk8(*(const float4*)p, *(const float4*)(p + 4));
}

// EDGE: A = [xb[dst] | xb[src] | attr(g3)], residual = attr. Plain args.
// NODE: A = [aggm(g1) | aggw(g2) | x(g3)],  residual = x. (W0 pre-rotated.)
template <bool EDGE>
__global__ __launch_bounds__(512, 4) void mlp_block(
    const float* __restrict__ g1, const float* __restrict__ g2,
    const float* __restrict__ g3, const unsigned short* __restrict__ xb,
    const int* __restrict__ srcI, const int* __restrict__ dstI,
    const unsigned short* __restrict__ Wt,
    const float* __restrict__ b0, const float* __restrict__ b1,
    const float* __restrict__ b2, const float* __restrict__ gam,
    const float* __restrict__ bet, float* __restrict__ outp, int M) {
  __shared__ __align__(16) char sm[SMEM];
  const int tid = threadIdx.x, lane = tid & 63, wave = tid >> 6;
  const int lrow = lane & 15, cg = lane >> 4;
  const unsigned short* Wt0 = Wt;
  const unsigned short* Wt1 = Wt + 24576;
  const unsigned short* Wt2 = Wt + 40960;
  const int ntiles = (M + 63) >> 6;
  const int cg2 = wave & 3, rg = wave >> 2;

  // ---- stage bias/LN params into LDS ----
  for (int i = tid; i < 448; i += 512) {
    float v;
    if (i < 128) v = b0[i];
    else if (i < 256) v = b1[i - 128];
    else if (i < 320) v = b2[i - 256];
    else if (i < 384) v = gam[i - 320];
    else v = bet[i - 384];
    ((float*)(sm + OFF_PAR))[i] = v;
  }
  const float* PAR = (const float*)(sm + OFF_PAR);

  // ---- persistent weight fragments, deduped across waves ----
  bf16x8 w0f[6], w1f[4], w2f[4];
#pragma unroll
  for (int kk = 0; kk < 6; ++kk)
    w0f[kk] = *(const bf16x8*)(Wt0 + (wave * 16 + lrow) * 192 + kk * 32 + cg * 8);
#pragma unroll
  for (int kk = 0; kk < 4; ++kk)
    w1f[kk] = *(const bf16x8*)(Wt1 + (wave * 16 + lrow) * 128 + kk * 32 + cg * 8);
#pragma unroll
  for (int kk = 0; kk < 4; ++kk)
    w2f[kk] = *(const bf16x8*)(Wt2 + (cg2 * 16 + lrow) * 128 + kk * 32 + cg * 8);

  // staging map: row = (tid>>5)*4 + ((tid&31)>>3), float-octet oct = tid&7
  const int srow = (tid >> 5) * 4 + ((tid & 31) >> 3), oct = tid & 7;

  int4 pxd, pxs, pat;
  auto LOADT = [&](int tt) {
    const int row = tt * 64 + srow;
    if (EDGE) {
      const int d = dstI[row], s2 = srcI[row];
      pxd = *(const int4*)(xb + (size_t)d * 64 + oct * 8);
      pxs = *(const int4*)(xb + (size_t)s2 * 64 + oct * 8);
      pat = ldpk(g3 + (size_t)row * 64 + oct * 8);
    } else {
      const int rr = min(row, M - 1);
      pxd = ldpk(g1 + (size_t)rr * 64 + oct * 8);
      pxs = ldpk(g2 + (size_t)rr * 64 + oct * 8);
      pat = ldpk(g3 + (size_t)rr * 64 + oct * 8);
    }
  };
  auto STAGE = [&]() {
    char* a0 = sm + OFF_A + srow * 384;
    const int swz = (srow & 7) << 4;
    *(int4*)(a0 + ((oct * 16) ^ swz)) = pxd;
    *(int4*)(a0 + ((128 + oct * 16) ^ swz)) = pxs;
    *(int4*)(a0 + ((256 + oct * 16) ^ swz)) = pat;
  };

  int t = blockIdx.x;
  if (t >= ntiles) return;
  LOADT(t);
  STAGE();

  for (; t < ntiles; t += NBLK) {
    const int tn = t + NBLK;
    const bool more = tn < ntiles;
    __syncthreads();  // (a) A(t) + PAR visible
    if (more) LOADT(tn);  // next-tile global loads ride under the MFMA phases
    // ---------------- L0: A[192] -> H0[128], relu ----------------
    {
      const f32x4 bb0 = *(const f32x4*)(PAR + wave * 16 + cg * 4);
#pragma unroll
      for (int rt = 0; rt < 4; ++rt) {
        const int row = rt * 16 + lrow, swz = (row & 7) << 4;
        const char* ab = sm + OFF_A + row * 384;
        f32x4 acc = {0.f, 0.f, 0.f, 0.f};
#pragma unroll
        for (int kk = 0; kk < 6; ++kk)
          acc = MFMA(w0f[kk], *(const bf16x8*)(ab + ((kk * 64 + cg * 16) ^ swz)), acc);
        f32x4 h;
#pragma unroll
        for (int q = 0; q < 4; ++q) h[q] = fmaxf(acc[q] + bb0[q], 0.f);
        *(unsigned long long*)(sm + OFF_H0 + row * 256 + ((wave * 32 + cg * 8) ^ swz)) = pk4(h);
      }
    }
    __syncthreads();  // (c) H0 ready
    // ---------------- L1: H0 -> H1 (A[0,256) overlay), relu ----------------
    {
      const f32x4 bb1 = *(const f32x4*)(PAR + 128 + wave * 16 + cg * 4);
#pragma unroll
      for (int rt = 0; rt < 4; ++rt) {
        const int row = rt * 16 + lrow, swz = (row & 7) << 4;
        const char* hb = sm + OFF_H0 + row * 256;
        f32x4 acc = {0.f, 0.f, 0.f, 0.f};
#pragma unroll
        for (int kk = 0; kk < 4; ++kk)
          acc = MFMA(w1f[kk], *(const bf16x8*)(hb + ((kk * 64 + cg * 16) ^ swz)), acc);
        f32x4 h;
#pragma unroll
        for (int q = 0; q < 4; ++q) h[q] = fmaxf(acc[q] + bb1[q], 0.f);
        *(unsigned long long*)(sm + OFF_A + row * 384 + ((wave * 32 + cg * 8) ^ swz)) = pk4(h);
      }
    }
    __syncthreads();  // (d) H1 ready
    // ---------------- L2p: H1 -> acc + bias, LN partials ----------------
    f32x4 accE[2];
    {
      const f32x4 bb2 = *(const f32x4*)(PAR + 256 + cg2 * 16 + cg * 4);
#pragma unroll
      for (int j = 0; j < 2; ++j) {
        const int row = (rg * 2 + j) * 16 + lrow, swz = (row & 7) << 4;
        const char* hb = sm + OFF_A + row * 384;
        f32x4 acc = {0.f, 0.f, 0.f, 0.f};
#pragma unroll
        for (int kk = 0; kk < 4; ++kk)
          acc = MFMA(w2f[kk], *(const bf16x8*)(hb + ((kk * 64 + cg * 16) ^ swz)), acc);
#pragma unroll
        for (int q = 0; q < 4; ++q) acc[q] += bb2[q];
        float s = acc[0] + acc[1] + acc[2] + acc[3];
        float ss = acc[0] * acc[0] + acc[1] * acc[1] + acc[2] * acc[2] + acc[3] * acc[3];
        s += __shfl_xor(s, 16, 64); s += __shfl_xor(s, 32, 64);
        ss += __shfl_xor(ss, 16, 64); ss += __shfl_xor(ss, 32, 64);
        if (cg == 0) *(float2*)(sm + OFF_P + row * 32 + cg2 * 8) = make_float2(s, ss);
        accE[j] = acc;
      }
    }
    __syncthreads();  // (e) partials ready; A free for next stage
    // ---------------- epilogue: LN + residual(global, L2) + store ----------------
    {
      const f32x4 gv = *(const f32x4*)(PAR + 320 + cg2 * 16 + cg * 4);
      const f32x4 bv = *(const f32x4*)(PAR + 384 + cg2 * 16 + cg * 4);
#pragma unroll
      for (int j = 0; j < 2; ++j) {
        const int row = (rg * 2 + j) * 16 + lrow, gr = t * 64 + row;
        float4 p0 = *(const float4*)(sm + OFF_P + row * 32);
        float4 p1 = *(const float4*)(sm + OFF_P + row * 32 + 16);
        float s = p0.x + p0.z + p1.x + p1.z, ss = p0.y + p0.w + p1.y + p1.w;
        float mean = s * (1.f / 64.f);
        float var = fmaxf(ss * (1.f / 64.f) - mean * mean, 0.f);
        float inv = rsqrtf(var + 1e-5f);
        const int col = cg2 * 16 + cg * 4;
        const int grc = EDGE ? gr : min(gr, M - 1);
        const f32x4 r = *(const f32x4*)(g3 + (size_t)grc * 64 + col);
        f32x4 av = accE[j], o;
#pragma unroll
        for (int q = 0; q < 4; ++q) o[q] = (av[q] - mean) * inv * gv[q] + bv[q] + r[q];
        if (EDGE || gr < M) *(f32x4*)(outp + (size_t)gr * 64 + col) = o;
      }
    }
    if (more) STAGE();
  }
}

// ---- K_agg: CSR segment-sum, both sets, 4-wide row loads per lane-group ----
__global__ __launch_bounds__(256) void agg_k(const float* __restrict__ em,
                                             const float* __restrict__ ew,
                                             const int* __restrict__ permM,
                                             const int* __restrict__ permW,
                                             const int* __restrict__ rpM,
                                             const int* __restrict__ rpW,
                                             float* __restrict__ aggm,
                                             float* __restrict__ aggw) {
  const int lane = threadIdx.x & 63;
  const int r4 = lane >> 4, cq = lane & 15;
  const int w = (blockIdx.x * 256 + threadIdx.x) >> 6;
  const int nw = gridDim.x * 4;
  for (int dd = w; dd < 2 * NNODES; dd += nw) {
    const bool s1 = dd >= NNODES;
    const int d = s1 ? dd - NNODES : dd;
    const float* oute = s1 ? ew : em;
    const int* perm = s1 ? permW : permM;
    const int* rp = s1 ? rpW : rpM;
    const int s = rp[d], e = rp[d + 1];
    f32x4 a0 = {0.f, 0.f, 0.f, 0.f}, a1 = {0.f, 0.f, 0.f, 0.f};
    f32x4 a2 = {0.f, 0.f, 0.f, 0.f}, a3 = {0.f, 0.f, 0.f, 0.f};
    int j = s + r4;
    for (; j + 12 < e; j += 16) {
      const int p0 = perm[j], p1 = perm[j + 4], p2 = perm[j + 8], p3 = perm[j + 12];
      const f32x4 v0 = *(const f32x4*)(oute + (size_t)p0 * 64 + cq * 4);
      const f32x4 v1 = *(const f32x4*)(oute + (size_t)p1 * 64 + cq * 4);
      const f32x4 v2 = *(const f32x4*)(oute + (size_t)p2 * 64 + cq * 4);
      const f32x4 v3 = *(const f32x4*)(oute + (size_t)p3 * 64 + cq * 4);
#pragma unroll
      for (int q = 0; q < 4; ++q) {
        a0[q] += v0[q]; a1[q] += v1[q]; a2[q] += v2[q]; a3[q] += v3[q];
      }
    }
    for (; j + 4 < e; j += 8) {
      const int p0 = perm[j], p1 = perm[j + 4];
      const f32x4 v0 = *(const f32x4*)(oute + (size_t)p0 * 64 + cq * 4);
      const f32x4 v1 = *(const f32x4*)(oute + (size_t)p1 * 64 + cq * 4);
#pragma unroll
      for (int q = 0; q < 4; ++q) { a0[q] += v0[q]; a1[q] += v1[q]; }
    }
    if (j < e) {
      const f32x4 v0 = *(const f32x4*)(oute + (size_t)perm[j] * 64 + cq * 4);
#pragma unroll
      for (int q = 0; q < 4; ++q) a0[q] += v0[q];
    }
#pragma unroll
    for (int q = 0; q < 4; ++q) {
      a0[q] += a1[q] + a2[q] + a3[q];
      a0[q] += __shfl_xor(a0[q], 16, 64);
      a0[q] += __shfl_xor(a0[q], 32, 64);
    }
    float* agg = s1 ? aggw : aggm;
    if (r4 == 0) *(f32x4*)(agg + (size_t)d * 64 + cq * 4) = a0;
  }
}

// ---- prep: weights -> bf16 [out][in] (upd-W0 rotated); x -> bf16 table ----
struct PrepArgs { const float* w[9]; unsigned short* wt[3]; };

__global__ void prep_w(PrepArgs pa) {
  int i = blockIdx.x * 256 + threadIdx.x;
  if (i >= 3 * 49152) return;
  int mlp = i / 49152;
  int rem = i - mlp * 49152;
  int mat, off, K, N;
  if (rem < 24576)      { mat = 0; off = 0;     K = 192; N = 128; }
  else if (rem < 40960) { mat = 1; off = 24576; K = 128; N = 128; }
  else                  { mat = 2; off = 40960; K = 128; N = 64;  }
  int local = rem - off;
  int n = local / K, k = local - n * K;
  if (mlp == 2 && mat == 0) k = (k + 64) % 192;  // node concat [aggm|aggw|x]
  pa.wt[mlp][rem] = f2bf(pa.w[mlp * 3 + mat][k * N + n]);
}

__global__ void prep_x(const float* __restrict__ x, unsigned short* __restrict__ xb) {
  int i = blockIdx.x * 256 + threadIdx.x;
  if (i < NNODES * 8) *(int4*)(xb + (size_t)i * 8) = ldpk(x + (size_t)i * 8);
}

__global__ void zero_f4(float4* p, int n) {
  int i = blockIdx.x * blockDim.x + threadIdx.x;
  if (i < n) p[i] = make_float4(0.f, 0.f, 0.f, 0.f);
}

// ---- counting sort by dst: hist -> parallel chunk scan -> scatter ----
__global__ void hist_k(const int* __restrict__ dM, const int* __restrict__ dW,
                       int* __restrict__ curM, int* __restrict__ curW, int E) {
  int i = blockIdx.x * 256 + threadIdx.x;
  if (i < E) {
    atomicAdd(curM + dM[i], 1);
    atomicAdd(curW + dW[i], 1);
  }
}

__global__ __launch_bounds__(64) void csum_k(const int* __restrict__ curM,
                                             const int* __restrict__ curW,
                                             int* __restrict__ csum) {
  const int c = blockIdx.x, set = c >= NCHUNK, c0 = c - set * NCHUNK;
  const int* cnt = set ? curW : curM;
  const int lane = threadIdx.x;
  const int base = c0 * 256 + lane * 4;
  int s = 0;
  if (base + 3 < NNODES) {
    int4 v = *(const int4*)(cnt + base);
    s = v.x + v.y + v.z + v.w;
  } else {
    for (int k = 0; k < 4; ++k) if (base + k < NNODES) s += cnt[base + k];
  }
#pragma unroll
  for (int off = 1; off < 64; off <<= 1) s += __shfl_xor(s, off, 64);
  if (lane == 0) csum[c] = s;
}

__global__ __launch_bounds__(512) void cscan_k(const int* __restrict__ csum,
                                               int* __restrict__ cbase) {
  __shared__ int buf[512];
  const int tid = threadIdx.x;
  buf[tid] = (tid < 2 * NCHUNK) ? csum[tid] : 0;
  __syncthreads();
  for (int off = 1; off < 512; off <<= 1) {
    int nv = (tid >= off) ? buf[tid - off] : 0;
    __syncthreads();
    buf[tid] += nv;
    __syncthreads();
  }
  if (tid < 2 * NCHUNK) {
    const int set = tid >= NCHUNK;
    int excl = tid ? buf[tid - 1] : 0;
    if (set) excl -= buf[NCHUNK - 1];
    cbase[tid] = excl;
  }
}

__global__ __launch_bounds__(64) void rp_k(int* __restrict__ curM, int* __restrict__ curW,
                                           const int* __restrict__ cbase,
                                           int* __restrict__ rpM, int* __restrict__ rpW) {
  const int c = blockIdx.x, set = c >= NCHUNK, c0 = c - set * NCHUNK;
  int* cnt = set ? curW : curM;
  int* rp = set ? rpW : rpM;
  const int lane = threadIdx.x;
  const int idx = c0 * 256 + lane * 4;
  int v[4];
#pragma unroll
  for (int k = 0; k < 4; ++k) v[k] = (idx + k < NNODES) ? cnt[idx + k] : 0;
  const int ls = v[0] + v[1] + v[2] + v[3];
  int ex = ls;
#pragma unroll
  for (int off = 1; off < 64; off <<= 1) {
    int nv = __shfl_up(ex, off, 64);
    if (lane >= off) ex += nv;
  }
  int run = cbase[c] + (ex - ls);
#pragma unroll
  for (int k = 0; k < 4; ++k) {
    if (idx + k < NNODES) {
      rp[idx + k] = run;
      cnt[idx + k] = run;
      run += v[k];
    }
  }
  if (c0 == 0 && lane == 0) rp[NNODES] = NEDGES;
}

__global__ void scatter_k(const int* __restrict__ dM, const int* __restrict__ dW,
                          int* __restrict__ curM, int* __restrict__ curW,
                          int* __restrict__ permM, int* __restrict__ permW, int E) {
  int i = blockIdx.x * 256 + threadIdx.x;
  if (i < E) {
    int p = atomicAdd(curM + dM[i], 1);
    permM[p] = i;
    p = atomicAdd(curW + dW[i], 1);
    permW[p] = i;
  }
}

extern "C" void kernel_launch(void* const* d_in, const int* in_sizes, int n_in,
                              void* d_out, int out_size, void* d_ws, size_t ws_size,
                              hipStream_t stream) {
  const float* x      = (const float*)d_in[0];
  const int*   meIdx  = (const int*)d_in[1];
  const float* meAttr = (const float*)d_in[2];
  const int*   weIdx  = (const int*)d_in[3];
  const float* weAttr = (const float*)d_in[4];

  float* out_x  = (float*)d_out;
  float* out_em = out_x + (size_t)NNODES * 64;
  float* out_ew = out_em + (size_t)NEDGES * 64;

  char* ws = (char*)d_ws;
  unsigned short* WtM = (unsigned short*)ws;                    // 3 x 98304
  unsigned short* WtW = (unsigned short*)(ws + 98304);
  unsigned short* WtU = (unsigned short*)(ws + 196608);
  unsigned short* xb  = (unsigned short*)(ws + 294912);         // 6.4 MB
  float* aggm = (float*)(ws + 6694912);                         // 12.8 MB
  float* aggw = (float*)(ws + 19494912);                        // 12.8 MB
  char* p = ws + 32294912;
  int* curM  = (int*)p;                                         // 200 KB
  int* curW  = curM + NNODES;                                   // 200 KB
  int* rpM   = (int*)(p + 400000);                              // 50016 ints
  int* rpW   = rpM + 50016;
  int* permM = rpW + 50016;                                     // 3.2 MB
  int* permW = permM + NEDGES;                                  // 3.2 MB
  int* csum  = permW + NEDGES;                                  // 392 ints
  int* cbase = csum + 512;                                      // end ~39.5 MB

  zero_f4<<<dim3(98), dim3(256), 0, stream>>>((float4*)curM, 25000);

  PrepArgs pa;
  for (int m = 0; m < 3; ++m)
    for (int l = 0; l < 3; ++l)
      pa.w[m * 3 + l] = (const float*)d_in[5 + m * 8 + l * 2];
  pa.wt[0] = WtM; pa.wt[1] = WtW; pa.wt[2] = WtU;
  prep_w<<<dim3(576), dim3(256), 0, stream>>>(pa);
  prep_x<<<dim3(1563), dim3(256), 0, stream>>>(x, xb);

  hist_k<<<dim3(3125), dim3(256), 0, stream>>>(meIdx + NEDGES, weIdx + NEDGES, curM, curW, NEDGES);
  csum_k<<<dim3(2 * NCHUNK), dim3(64), 0, stream>>>(curM, curW, csum);
  cscan_k<<<dim3(1), dim3(512), 0, stream>>>(csum, cbase);
  rp_k<<<dim3(2 * NCHUNK), dim3(64), 0, stream>>>(curM, curW, cbase, rpM, rpW);
  scatter_k<<<dim3(3125), dim3(256), 0, stream>>>(meIdx + NEDGES, weIdx + NEDGES,
                                                  curM, curW, permM, permW, NEDGES);

  // edge MLPs (original order; x_i = x[dst], x_j = x[src])
  mlp_block<true><<<dim3(NBLK), dim3(512), 0, stream>>>(
      nullptr, nullptr, meAttr, xb, meIdx, meIdx + NEDGES, WtM,
      (const float*)d_in[6], (const float*)d_in[8], (const float*)d_in[10],
      (const float*)d_in[11], (const float*)d_in[12],
      out_em, NEDGES);
  mlp_block<true><<<dim3(NBLK), dim3(512), 0, stream>>>(
      nullptr, nullptr, weAttr, xb, weIdx, weIdx + NEDGES, WtW,
      (const float*)d_in[14], (const float*)d_in[16], (const float*)d_in[18],
      (const float*)d_in[19], (const float*)d_in[20],
      out_ew, NEDGES);

  // merged CSR segment sums (4-wide ILP)
  agg_k<<<dim3(4096), dim3(256), 0, stream>>>(out_em, out_ew, permM, permW, rpM, rpW, aggm, aggw);

  // node update: A = [aggm | aggw | x], residual = x
  mlp_block<false><<<dim3(NBLK), dim3(512), 0, stream>>>(
      aggm, aggw, x, nullptr, nullptr, nullptr, WtU,
      (const float*)d_in[22], (const float*)d_in[24], (const float*)d_in[26],
      (const float*)d_in[27], (const float*)d_in[28],
      out_x, NNODES);
}